// Round 11
// baseline (1072.842 us; speedup 1.0000x reference)
//
#include <hip/hip_runtime.h>
#include <cstdint>

typedef __attribute__((ext_vector_type(8))) short bf16x8;
typedef __attribute__((ext_vector_type(16))) float f32x16;

#define BN_NB 256
#define LRELU_SLOPE 0.1f
#define GTILE 128   // P-rows per pair-GEMM block

__device__ __forceinline__ float bf2f(ushort h) {
    union { uint u; float v; } x; x.u = ((uint)h) << 16; return x.v;
}
__device__ __forceinline__ ushort f2bf(float f) {
    union { float v; uint u; } x; x.v = f;
    const uint r = (x.u + 0x7FFFu + ((x.u >> 16) & 1u)) >> 16;  // RNE
    return (ushort)r;
}

// async 16B global->LDS (wave-uniform LDS base + lane*16)
__device__ __forceinline__ void gload_lds16(const void* g, void* l) {
    __builtin_amdgcn_global_load_lds((const __attribute__((address_space(1))) void*)g,
                                     (__attribute__((address_space(3))) void*)l, 16, 0, 0);
}

// ---------------------------------------------------------------------------
// Zero per-call state: 3x128-int counter blocks + sentinel zero feature rows.
// ---------------------------------------------------------------------------
__global__ __launch_bounds__(256) void zero_init(int* __restrict__ ctrs,
                                                 ushort* __restrict__ xbz,
                                                 ushort* __restrict__ f1z,
                                                 ushort* __restrict__ f2z)
{
    const int t = threadIdx.x;
    for (int i = t; i < 384; i += 256) ctrs[i] = 0;
    if (t < 96) xbz[t] = 0;
    if (t < 64) { f1z[t] = 0; f2z[t] = 0; }
}

// ---------------------------------------------------------------------------
// x (fp32) -> bf16, vectorized
// ---------------------------------------------------------------------------
__global__ __launch_bounds__(256) void cvt_bf16(const float* __restrict__ in,
                                                ushort* __restrict__ out, int n4)
{
    for (int i = blockIdx.x * 256 + threadIdx.x; i < n4; i += gridDim.x * 256) {
        const float4 v = reinterpret_cast<const float4*>(in)[i];
        ushort4 o;
        o.x = f2bf(v.x); o.y = f2bf(v.y); o.z = f2bf(v.z); o.w = f2bf(v.w);
        reinterpret_cast<ushort4*>(out)[i] = o;
    }
}

// ---------------------------------------------------------------------------
// Pack W[K][CIN][64] fp32 -> bf16 B-fragments for mfma_f32_32x32x16_bf16.
// Chunk c = ks*2 + ct; lane l holds W[tap][ks*16+(l>>5)*8+e][ct*32+(l&31)].
// ---------------------------------------------------------------------------
template<int K, int CIN>
__global__ __launch_bounds__(256) void pack_W(const float* __restrict__ W,
                                              ushort* __restrict__ Bp)
{
    constexpr int KS = CIN / 16;
    constexpr int CHUNKS = KS * 2;
    const int t = blockIdx.x * 256 + threadIdx.x;
    if (t >= K * CHUNKS * 64) return;
    const int l = t & 63;
    const int s = t >> 6;
    const int c = s % CHUNKS;
    const int tap = s / CHUNKS;
    const int ks = c >> 1;
    const int ct = c & 1;
    const int k0 = ks * 16 + (l >> 5) * 8;
    const int col = ct * 32 + (l & 31);
    bf16x8 v;
#pragma unroll
    for (int e = 0; e < 8; ++e)
        v[e] = (short)f2bf(W[((size_t)tap * CIN + k0 + e) * 64 + col]);
    *reinterpret_cast<bf16x8*>(Bp + (size_t)t * 8) = v;
}

// ---------------------------------------------------------------------------
// pk1: count valid pairs per tap (wave-aggregated atomics; k is uniform).
// ---------------------------------------------------------------------------
template<int K>
__global__ __launch_bounds__(256) void pk1_count(const int* __restrict__ nmap, int nout, int nin,
                                                 int* __restrict__ cnt)
{
    const int r = blockIdx.x * 256 + threadIdx.x;
    if (r >= nout) return;
    const int* base = nmap + (size_t)r * K;
#pragma unroll
    for (int k = 0; k < K; ++k)
        if (base[k] < nin) atomicAdd(&cnt[k], 1);
}

// ---------------------------------------------------------------------------
// pk2: scan counts -> tapstart ts[0..K] (at ctr+64), cur init (ctr+32),
// ntiles (ctr[96]), and fill tilemap[t] = (tap<<16)|tile_in_tap.
// ---------------------------------------------------------------------------
template<int K>
__global__ __launch_bounds__(64) void pk2_setup(int* __restrict__ ctr,
                                                int* __restrict__ tilemap)
{
    __shared__ int ts[K + 1], tof[K + 1];
    const int t = threadIdx.x;
    if (t == 0) {
        int acc = 0, nt = 0;
        for (int k = 0; k < K; ++k) {
            ts[k] = acc; tof[k] = nt;
            const int c = ctr[k];
            acc += c;
            nt += (c + GTILE - 1) / GTILE;
        }
        ts[K] = acc; tof[K] = nt;
        ctr[96] = nt;
    }
    __syncthreads();
    if (t < K + 1) ctr[64 + t] = ts[t];
    if (t < K)     ctr[32 + t] = ts[t];   // cur init
    for (int k = 0; k < K; ++k) {
        const int tiles = tof[k + 1] - tof[k];
        for (int j = t; j < tiles; j += 64)
            tilemap[tof[k] + j] = (k << 16) | j;
    }
}

// ---------------------------------------------------------------------------
// pk3: assign P-slots (aggregated atomic on cur[k]); pos[k][r] = slot or -1;
// IL[slot] = input row index. Slot order varies per run but the OUTPUT is
// bit-deterministic: each pair's product is row-independent in MFMA and the
// reduce sums in fixed k-order via pos.
// ---------------------------------------------------------------------------
template<int K>
__global__ __launch_bounds__(256) void pk3_fill(const int* __restrict__ nmap, int nout, int nin,
                                                int* __restrict__ cur,
                                                int* __restrict__ pos,
                                                int* __restrict__ IL)
{
    const int r = blockIdx.x * 256 + threadIdx.x;
    if (r >= nout) return;
    const int* base = nmap + (size_t)r * K;
#pragma unroll
    for (int k = 0; k < K; ++k) {
        const int idx = base[k];
        int slot = -1;
        if (idx < nin) {
            slot = atomicAdd(&cur[32 + k - 32], 1);   // cur block passed directly
            IL[slot] = idx;
        }
        pos[(size_t)k * nout + r] = slot;
    }
}

// ---------------------------------------------------------------------------
// pair-GEMM: per tile (tap k, 128 valid pairs) one dense MFMA pass.
// Block: 256 thr = 4 waves x 32 P-rows; B slice for tap k staged ONCE into
// LDS via global_load_lds; A gathered per-lane from fin (valid pairs only).
// P[slot][64] written coalesced (bf16). Tail rows use the zero feature row.
// ---------------------------------------------------------------------------
template<int K, int CIN>
__global__ __launch_bounds__(256) void pair_gemm(
    const ushort* __restrict__ fin, int nin,
    const int* __restrict__ IL,
    const int* __restrict__ ctr,      // ts at +64, ntiles at +96
    const int* __restrict__ tilemap,
    const ushort* __restrict__ Bp,
    ushort* __restrict__ P)
{
    constexpr int KS = CIN / 16;
    constexpr int CH = KS * 2;
    constexpr int CPW = CH / 4;       // B chunks staged per wave
    __shared__ ushort Bb[CH * 512];

    const int tid = threadIdx.x;
    const int l = tid & 63;
    const int w = tid >> 6;
    const int lrow = l & 31;
    const int hi = l >> 5;
    const int ntiles = ctr[96];
    const int* ts = ctr + 64;

    for (int t = blockIdx.x; t < ntiles; t += gridDim.x) {
        const int info = tilemap[t];
        const int k = info >> 16;
        const int j = info & 0xFFFF;
        const int tsk = ts[k];
        const int cntk = ts[k + 1] - tsk;
        const int rbase = j * GTILE;

        // stage B slice for tap k (uniform LDS base per wave)
#pragma unroll
        for (int c = 0; c < CPW; ++c) {
            const int cc = w * CPW + c;
            gload_lds16(Bp + ((size_t)k * CH + cc) * 512 + l * 8, &Bb[cc * 512]);
        }

        const int rin = rbase + w * 32 + lrow;               // row within tap
        const int idx = (rin < cntk) ? IL[tsk + rin] : nin;  // tail -> zero row
        const ushort* rp = fin + (size_t)idx * CIN + hi * 8;
        __syncthreads();   // B staged & visible (vmcnt drain at barrier)

        bf16x8 a[KS];
#pragma unroll
        for (int ks = 0; ks < KS; ++ks)
            a[ks] = *reinterpret_cast<const bf16x8*>(rp + ks * 16);

        f32x16 acc0, acc1;
#pragma unroll
        for (int q = 0; q < 16; ++q) { acc0[q] = 0.f; acc1[q] = 0.f; }
#pragma unroll
        for (int ks = 0; ks < KS; ++ks) {
            const bf16x8 b0 = *reinterpret_cast<const bf16x8*>(&Bb[(ks * 2 + 0) * 512 + l * 8]);
            acc0 = __builtin_amdgcn_mfma_f32_32x32x16_bf16(a[ks], b0, acc0, 0, 0, 0);
            const bf16x8 b1 = *reinterpret_cast<const bf16x8*>(&Bb[(ks * 2 + 1) * 512 + l * 8]);
            acc1 = __builtin_amdgcn_mfma_f32_32x32x16_bf16(a[ks], b1, acc1, 0, 0, 0);
        }

        // write P: D col = ct*32 + (l&31), row = (reg&3)+8*(reg>>2)+4*hi
        const int prow0 = tsk + rbase + w * 32;
#pragma unroll
        for (int reg = 0; reg < 16; ++reg) {
            const int rowD = (reg & 3) + 8 * (reg >> 2) + 4 * hi;
            if (rbase + w * 32 + rowD < cntk) {
                ushort* pp = P + (size_t)(prow0 + rowD) * 64 + lrow;
                pp[0]  = f2bf(acc0[reg]);
                pp[32] = f2bf(acc1[reg]);
            }
        }
        __syncthreads();   // all reads done before next tile's stage
    }
}

// ---------------------------------------------------------------------------
// pair-reduce: out[r] = act( sum_{k valid} P[pos[k][r]] + bias ).
// pos reads coalesced (fixed k, consecutive r); P rows gathered 128B/row.
// ---------------------------------------------------------------------------
template<int K, bool LEAKY, bool OUTF32>
__global__ __launch_bounds__(256) void pair_reduce(
    const int* __restrict__ pos, int nout,
    const ushort* __restrict__ P,
    const float* __restrict__ bias,
    void* __restrict__ fout)
{
    const int r = blockIdx.x * 256 + threadIdx.x;
    if (r >= nout) return;
    float acc[64];
#pragma unroll
    for (int c = 0; c < 64; ++c) acc[c] = 0.f;
#pragma unroll
    for (int k = 0; k < K; ++k) {
        const int p = pos[(size_t)k * nout + r];
        if (p >= 0) {
            const ushort* pr = P + (size_t)p * 64;
#pragma unroll
            for (int q = 0; q < 8; ++q) {
                const bf16x8 v = *reinterpret_cast<const bf16x8*>(pr + q * 8);
#pragma unroll
                for (int e = 0; e < 8; ++e)
                    acc[q * 8 + e] += bf2f((ushort)v[e]);
            }
        }
    }
    if (OUTF32) {
        float* o = reinterpret_cast<float*>(fout) + (size_t)r * 64;
#pragma unroll
        for (int c = 0; c < 64; ++c) {
            float v = acc[c] + bias[c];
            if (LEAKY) v = v >= 0.f ? v : LRELU_SLOPE * v;
            o[c] = v;
        }
    } else {
        ushort* o = reinterpret_cast<ushort*>(fout) + (size_t)r * 64;
#pragma unroll
        for (int c = 0; c < 64; ++c) {
            float v = acc[c] + bias[c];
            if (LEAKY) v = v >= 0.f ? v : LRELU_SLOPE * v;
            o[c] = f2bf(v);
        }
    }
}

// ---------------------------------------------------------------------------
// BatchNorm stage 1 (bf16 input): deterministic per-block partial sum/sumsq.
// ---------------------------------------------------------------------------
__global__ __launch_bounds__(256) void bn_partial(const ushort* __restrict__ f2v, int n2,
                                                  float* __restrict__ partials)
{
    const int c = threadIdx.x & 63;
    const int g = threadIdx.x >> 6;
    float s = 0.f, ss = 0.f;
    for (int r = blockIdx.x * 4 + g; r < n2; r += gridDim.x * 4) {
        const float v = bf2f(f2v[(size_t)r * 64 + c]);
        s += v;
        ss = fmaf(v, v, ss);
    }
    __shared__ float red[4][128];
    red[g][c] = s;
    red[g][64 + c] = ss;
    __syncthreads();
    if (g == 0) {
        partials[(size_t)blockIdx.x * 128 + c] =
            red[0][c] + red[1][c] + red[2][c] + red[3][c];
        partials[(size_t)blockIdx.x * 128 + 64 + c] =
            red[0][64 + c] + red[1][64 + c] + red[2][64 + c] + red[3][64 + c];
    }
}

// ---------------------------------------------------------------------------
// BatchNorm stage 2: PARALLEL final reduce -> per-channel affine (scale folded)
// ---------------------------------------------------------------------------
__global__ __launch_bounds__(1024) void bn_finalize(const float* __restrict__ partials, int n2,
                                                    const float* __restrict__ gamma,
                                                    const float* __restrict__ beta,
                                                    const float* __restrict__ scale,
                                                    float* __restrict__ affA, float* __restrict__ affB)
{
    const int t = threadIdx.x;
    const int col = t & 127;
    const int g = t >> 7;
    float s = 0.f;
#pragma unroll
    for (int b = g; b < BN_NB; b += 8)
        s += partials[(size_t)b * 128 + col];
    __shared__ float red[8][128];
    red[g][col] = s;
    __syncthreads();
    if (g == 0) {
        float S = red[0][col];
#pragma unroll
        for (int i = 1; i < 8; ++i) S += red[i][col];
        red[0][col] = S;
    }
    __syncthreads();
    if (t < 64) {
        const float S = red[0][t];
        const float SS = red[0][64 + t];
        const float inv_n = 1.f / (float)n2;
        const float mu = S * inv_n;
        const float var = fmaxf(SS * inv_n - mu * mu, 0.f);
        const float rs = rsqrtf(var + 1e-5f);
        const float sc = scale[0];
        const float ga = gamma[t];
        affA[t] = rs * ga * sc;
        affB[t] = (beta[t] - mu * rs * ga) * sc;
    }
}

// ---------------------------------------------------------------------------
// In-place BN affine on f2 (bf16): f2 = f2*a + b.
// ---------------------------------------------------------------------------
__global__ __launch_bounds__(256) void aff_apply(ushort* __restrict__ f2, int nchunk,
                                                 const float* __restrict__ affA,
                                                 const float* __restrict__ affB)
{
    for (int i = blockIdx.x * 256 + threadIdx.x; i < nchunk; i += gridDim.x * 256) {
        const int c = i & 7;
        bf16x8 v = *reinterpret_cast<const bf16x8*>(f2 + (size_t)i * 8);
#pragma unroll
        for (int j = 0; j < 8; ++j)
            v[j] = (short)f2bf(fmaf(bf2f((ushort)v[j]), affA[c * 8 + j], affB[c * 8 + j]));
        *reinterpret_cast<bf16x8*>(f2 + (size_t)i * 8) = v;
    }
}

extern "C" void kernel_launch(void* const* d_in, const int* in_sizes, int n_in,
                              void* d_out, int out_size, void* d_ws, size_t ws_size,
                              hipStream_t stream)
{
    const float* x     = (const float*)d_in[0];
    const float* W1    = (const float*)d_in[1];
    const float* b1    = (const float*)d_in[2];
    const float* W2    = (const float*)d_in[3];
    const float* b2    = (const float*)d_in[4];
    const float* W3    = (const float*)d_in[5];
    const float* b3    = (const float*)d_in[6];
    const float* gamma = (const float*)d_in[7];
    const float* beta  = (const float*)d_in[8];
    const float* scale = (const float*)d_in[9];
    const int* nmap1   = (const int*)d_in[10];
    const int* nmap2   = (const int*)d_in[11];
    const int* nmap3   = (const int*)d_in[12];

    const int N  = in_sizes[0] / 96;    // stride-1 points
    const int N2 = in_sizes[11] / 8;    // stride-2 points
    const int E1 = 27 * N;              // max pairs (sizes pos/IL/P)

    // ---- workspace layout (ushort units; every region 16B-aligned) ----
    ushort* xb  = (ushort*)d_ws;                    // [N+1,96] bf16
    ushort* f1  = xb + (size_t)(N + 1) * 96;        // [N+1,64] bf16
    ushort* f2  = f1 + (size_t)(N + 1) * 64;        // [N2+1,64] bf16
    ushort* Bp1 = f2 + (size_t)(N2 + 1) * 64;       // 27*96*64
    ushort* Bp2 = Bp1 + 27 * 96 * 64;               // 8*64*64
    ushort* Bp3 = Bp2 + 8 * 64 * 64;                // 27*64*64
    float* partials = (float*)(Bp3 + 27 * 64 * 64); // [BN_NB,128] f32
    float* affA = partials + (size_t)BN_NB * 128;   // [64]
    float* affB = affA + 64;                        // [64]
    int* ctrs   = (int*)(affB + 64);                // 3 x 128 ints
    int* tmap   = ctrs + 384;                       // 16384 ints
    int* pos    = tmap + 16384;                     // E1 ints
    int* IL     = pos + E1;                         // E1 ints
    ushort* P   = (ushort*)(IL + E1);               // [E1, 64] bf16
    float* out  = (float*)d_out;                    // [N2,64] fp32

    int* c1 = ctrs, * c2 = ctrs + 128, * c3 = ctrs + 256;

    const int gN  = (N + 255) / 256;
    const int gN2 = (N2 + 255) / 256;

    // ---- prologue ----
    zero_init<<<1, 256, 0, stream>>>(ctrs, xb + (size_t)N * 96,
                                     f1 + (size_t)N * 64, f2 + (size_t)N2 * 64);
    cvt_bf16<<<2048, 256, 0, stream>>>(x, xb, N * 96 / 4);
    pack_W<27, 96><<<(27 * 12 * 64 + 255) / 256, 256, 0, stream>>>(W1, Bp1);
    pack_W<8, 64><<<(8 * 8 * 64 + 255) / 256, 256, 0, stream>>>(W2, Bp2);
    pack_W<27, 64><<<(27 * 8 * 64 + 255) / 256, 256, 0, stream>>>(W3, Bp3);

    // ---- conv1: k=27, 96->64, leaky ----
    pk1_count<27><<<gN, 256, 0, stream>>>(nmap1, N, N, c1);
    pk2_setup<27><<<1, 64, 0, stream>>>(c1, tmap);
    pk3_fill<27><<<gN, 256, 0, stream>>>(nmap1, N, N, c1 + 32, pos, IL);
    pair_gemm<27, 96><<<2048, 256, 0, stream>>>(xb, N, IL, c1, tmap, Bp1, P);
    pair_reduce<27, true, false><<<gN, 256, 0, stream>>>(pos, N, P, b1, f1);

    // ---- conv2: k=8, 64->64, leaky (downsample) ----
    pk1_count<8><<<gN2, 256, 0, stream>>>(nmap2, N2, N, c2);
    pk2_setup<8><<<1, 64, 0, stream>>>(c2, tmap);
    pk3_fill<8><<<gN2, 256, 0, stream>>>(nmap2, N2, N, c2 + 32, pos, IL);
    pair_gemm<8, 64><<<2048, 256, 0, stream>>>(f1, N, IL, c2, tmap, Bp2, P);
    pair_reduce<8, true, false><<<gN2, 256, 0, stream>>>(pos, N2, P, b2, f2);

    // ---- batchnorm (deterministic two-stage) + in-place affine ----
    bn_partial<<<BN_NB, 256, 0, stream>>>(f2, N2, partials);
    bn_finalize<<<1, 1024, 0, stream>>>(partials, N2, gamma, beta, scale, affA, affB);
    aff_apply<<<2048, 256, 0, stream>>>(f2, N2 * 8, affA, affB);

    // ---- conv3: k=27, 64->64, fp32 out ----
    pk1_count<27><<<gN2, 256, 0, stream>>>(nmap3, N2, N2, c3);
    pk2_setup<27><<<1, 64, 0, stream>>>(c3, tmap);
    pk3_fill<27><<<gN2, 256, 0, stream>>>(nmap3, N2, N2, c3 + 32, pos, IL);
    pair_gemm<27, 64><<<2048, 256, 0, stream>>>(f2, N2, IL, c3, tmap, Bp3, P);
    pair_reduce<27, false, true><<<gN2, 256, 0, stream>>>(pos, N2, P, b3, out);
}

// Round 12
// 238.474 us; speedup vs baseline: 4.4988x; 4.4988x over previous
//
#include <hip/hip_runtime.h>
#include <cstdint>

typedef __attribute__((ext_vector_type(8))) short bf16x8;
typedef __attribute__((ext_vector_type(16))) float f32x16;

#define BN_NB 256
#define LRELU_SLOPE 0.1f
#define GTILE 128   // P-rows per pair-GEMM tile

__device__ __forceinline__ float bf2f(ushort h) {
    union { uint u; float v; } x; x.u = ((uint)h) << 16; return x.v;
}
__device__ __forceinline__ ushort f2bf(float f) {
    union { float v; uint u; } x; x.v = f;
    const uint r = (x.u + 0x7FFFu + ((x.u >> 16) & 1u)) >> 16;  // RNE
    return (ushort)r;
}

// async 16B global->LDS (wave-uniform LDS base + lane*16)
__device__ __forceinline__ void gload_lds16(const void* g, void* l) {
    __builtin_amdgcn_global_load_lds((const __attribute__((address_space(1))) void*)g,
                                     (__attribute__((address_space(3))) void*)l, 16, 0, 0);
}

// ---------------------------------------------------------------------------
// Zero sentinel feature rows.
// ---------------------------------------------------------------------------
__global__ __launch_bounds__(128) void zero_rows(ushort* __restrict__ xbz,
                                                 ushort* __restrict__ f1z,
                                                 ushort* __restrict__ f2z)
{
    const int t = threadIdx.x;
    if (t < 96) xbz[t] = 0;
    if (t < 64) { f1z[t] = 0; f2z[t] = 0; }
}

// ---------------------------------------------------------------------------
// x (fp32) -> bf16, vectorized
// ---------------------------------------------------------------------------
__global__ __launch_bounds__(256) void cvt_bf16(const float* __restrict__ in,
                                                ushort* __restrict__ out, int n4)
{
    for (int i = blockIdx.x * 256 + threadIdx.x; i < n4; i += gridDim.x * 256) {
        const float4 v = reinterpret_cast<const float4*>(in)[i];
        ushort4 o;
        o.x = f2bf(v.x); o.y = f2bf(v.y); o.z = f2bf(v.z); o.w = f2bf(v.w);
        reinterpret_cast<ushort4*>(out)[i] = o;
    }
}

// ---------------------------------------------------------------------------
// Pack W[K][CIN][64] fp32 -> bf16 B-fragments for mfma_f32_32x32x16_bf16.
// Chunk c = ks*2 + ct; lane l holds W[tap][ks*16+(l>>5)*8+e][ct*32+(l&31)].
// ---------------------------------------------------------------------------
template<int K, int CIN>
__global__ __launch_bounds__(256) void pack_W(const float* __restrict__ W,
                                              ushort* __restrict__ Bp)
{
    constexpr int KS = CIN / 16;
    constexpr int CHUNKS = KS * 2;
    const int t = blockIdx.x * 256 + threadIdx.x;
    if (t >= K * CHUNKS * 64) return;
    const int l = t & 63;
    const int s = t >> 6;
    const int c = s % CHUNKS;
    const int tap = s / CHUNKS;
    const int ks = c >> 1;
    const int ct = c & 1;
    const int k0 = ks * 16 + (l >> 5) * 8;
    const int col = ct * 32 + (l & 31);
    bf16x8 v;
#pragma unroll
    for (int e = 0; e < 8; ++e)
        v[e] = (short)f2bf(W[((size_t)tap * CIN + k0 + e) * 64 + col]);
    *reinterpret_cast<bf16x8*>(Bp + (size_t)t * 8) = v;
}

// ---------------------------------------------------------------------------
// pk1: per-(tap, block) valid-pair counts via ballot (NO atomics).
// cnt2d[k*nblk + blk] = # valid entries among this block's 256 rows.
// ---------------------------------------------------------------------------
template<int K>
__global__ __launch_bounds__(256) void pk1_count(const int* __restrict__ nmap,
                                                 int nout, int nin, int nblk,
                                                 int* __restrict__ cnt2d)
{
    __shared__ int wc[32][4];
    const int t = threadIdx.x;
    const int l = t & 63;
    const int w = t >> 6;
    const int rr = blockIdx.x * 256 + w * 64 + l;
    const bool inb = rr < nout;
    const int* bp = nmap + (size_t)rr * K;
#pragma unroll
    for (int k = 0; k < K; ++k) {
        const int idx = inb ? bp[k] : 0x7FFFFFFF;
        const unsigned long long m = __ballot(idx < nin);
        if (l == 0) wc[k][w] = __popcll(m);
    }
    __syncthreads();
    if (t < K)
        cnt2d[(size_t)t * nblk + blockIdx.x] = wc[t][0] + wc[t][1] + wc[t][2] + wc[t][3];
}

// ---------------------------------------------------------------------------
// pk2: one-block exclusive scan over flattened cnt2d[K*nblk] -> base2d;
// meta[0..K] = ts (tap starts), meta[64] = ntiles; tilemap filled.
// Hierarchical: chunk sums -> 256-entry Hillis-Steele -> chunk walk.
// ---------------------------------------------------------------------------
template<int K>
__global__ __launch_bounds__(256) void pk2_scan(const int* __restrict__ cnt2d, int nblk,
                                                int* __restrict__ base2d,
                                                int* __restrict__ meta,
                                                int* __restrict__ tilemap)
{
    __shared__ int buf[6600];
    __shared__ int psum[256];
    __shared__ int tofh[32];
    const int t = threadIdx.x;
    const int n = K * nblk;           // <= 27*235 = 6345
    const int chunk = (n + 255) / 256;
    const int lo = t * chunk;
    const int hi = min(n, lo + chunk);

    int s = 0;
    for (int i = lo; i < hi; ++i) { const int v = cnt2d[i]; buf[i] = v; s += v; }
    psum[t] = s;
    __syncthreads();
    // Hillis-Steele inclusive scan over 256 chunk sums
    for (int off = 1; off < 256; off <<= 1) {
        const int mine = psum[t];
        const int add = (t >= off) ? psum[t - off] : 0;
        __syncthreads();
        psum[t] = mine + add;
        __syncthreads();
    }
    // chunk walk: exclusive bases
    int run = (t > 0) ? psum[t - 1] : 0;
    for (int i = lo; i < hi; ++i) { base2d[i] = run; run += buf[i]; }
    __syncthreads();
    // ts[k] = exclusive prefix at flat index k*nblk; ts[K] = total
    if (t < K) meta[t] = base2d[(size_t)t * nblk];
    if (t == 0) meta[K] = psum[255];
    __syncthreads();
    // tiles per tap + tilemap
    if (t == 0) {
        int nt = 0;
        for (int k = 0; k < K; ++k) {
            tofh[k] = nt;
            const int c = ((k + 1 < K) ? meta[k + 1] : meta[K]) - meta[k];
            nt += (c + GTILE - 1) / GTILE;
        }
        tofh[K] = nt;
        meta[64] = nt;
    }
    __syncthreads();
    for (int k = 0; k < K; ++k) {
        const int tiles = tofh[k + 1] - tofh[k];
        for (int j = t; j < tiles; j += 256)
            tilemap[tofh[k] + j] = (k << 16) | j;
    }
}

// ---------------------------------------------------------------------------
// pk3: deterministic slot assignment (NO atomics).
// slot = base2d[k][blk] + (waves below, this block) + (lanes below, this wave).
// pos[k*nout + r] = slot or -1; IL[slot] = input row.
// ---------------------------------------------------------------------------
template<int K>
__global__ __launch_bounds__(256) void pk3_fill(const int* __restrict__ nmap,
                                                int nout, int nin, int nblk,
                                                const int* __restrict__ base2d,
                                                int* __restrict__ pos,
                                                int* __restrict__ IL)
{
    __shared__ int wc[32][4];
    const int t = threadIdx.x;
    const int l = t & 63;
    const int w = t >> 6;
    const int rr = blockIdx.x * 256 + w * 64 + l;
    const bool inb = rr < nout;
    const int* bp = nmap + (size_t)rr * K;
    const unsigned long long below = (1ULL << l) - 1ULL;

    int idxs[K];
#pragma unroll
    for (int k = 0; k < K; ++k) {
        idxs[k] = inb ? bp[k] : 0x7FFFFFFF;
        const unsigned long long m = __ballot(idxs[k] < nin);
        if (l == 0) wc[k][w] = __popcll(m);
    }
    __syncthreads();
#pragma unroll
    for (int k = 0; k < K; ++k) {
        const bool v = idxs[k] < nin;
        const unsigned long long m = __ballot(v);
        const int local = __popcll(m & below);
        int woff = 0;
#pragma unroll
        for (int ww = 0; ww < 4; ++ww) if (ww < w) woff += wc[k][ww];
        const int slot = base2d[(size_t)k * nblk + blockIdx.x] + woff + local;
        if (inb) pos[(size_t)k * nout + rr] = v ? slot : -1;
        if (v) IL[slot] = idxs[k];
    }
}

// ---------------------------------------------------------------------------
// pair-GEMM: per tile (tap k, 128 valid pairs) one dense MFMA pass.
// Block: 256 thr = 4 waves x 32 P-rows; B slice for tap k staged ONCE into
// LDS via global_load_lds; A gathered per-lane (valid pairs only).
// P[slot][64] written coalesced (bf16). Tail rows use the zero feature row.
// ---------------------------------------------------------------------------
template<int K, int CIN>
__global__ __launch_bounds__(256) void pair_gemm(
    const ushort* __restrict__ fin, int nin,
    const int* __restrict__ IL,
    const int* __restrict__ meta,     // ts at [0..K], ntiles at [64]
    const int* __restrict__ tilemap,
    const ushort* __restrict__ Bp,
    ushort* __restrict__ P)
{
    constexpr int KS = CIN / 16;
    constexpr int CH = KS * 2;
    constexpr int CPW = CH / 4;       // B chunks staged per wave
    __shared__ ushort Bb[CH * 512];

    const int tid = threadIdx.x;
    const int l = tid & 63;
    const int w = tid >> 6;
    const int lrow = l & 31;
    const int hi = l >> 5;
    const int ntiles = meta[64];

    for (int t = blockIdx.x; t < ntiles; t += gridDim.x) {
        const int info = tilemap[t];
        const int k = info >> 16;
        const int j = info & 0xFFFF;
        const int tsk = meta[k];
        const int cntk = ((k + 1 < K) ? meta[k + 1] : meta[K]) - tsk;
        const int rbase = j * GTILE;

        // stage B slice for tap k
#pragma unroll
        for (int c = 0; c < CPW; ++c) {
            const int cc = w * CPW + c;
            gload_lds16(Bp + ((size_t)k * CH + cc) * 512 + l * 8, &Bb[cc * 512]);
        }

        const int rin = rbase + w * 32 + lrow;               // row within tap
        const int idx = (rin < cntk) ? IL[tsk + rin] : nin;  // tail -> zero row
        const ushort* rp = fin + (size_t)idx * CIN + hi * 8;
        __syncthreads();   // B staged & visible

        bf16x8 a[KS];
#pragma unroll
        for (int ks = 0; ks < KS; ++ks)
            a[ks] = *reinterpret_cast<const bf16x8*>(rp + ks * 16);

        f32x16 acc0, acc1;
#pragma unroll
        for (int q = 0; q < 16; ++q) { acc0[q] = 0.f; acc1[q] = 0.f; }
#pragma unroll
        for (int ks = 0; ks < KS; ++ks) {
            const bf16x8 b0 = *reinterpret_cast<const bf16x8*>(&Bb[(ks * 2 + 0) * 512 + l * 8]);
            acc0 = __builtin_amdgcn_mfma_f32_32x32x16_bf16(a[ks], b0, acc0, 0, 0, 0);
            const bf16x8 b1 = *reinterpret_cast<const bf16x8*>(&Bb[(ks * 2 + 1) * 512 + l * 8]);
            acc1 = __builtin_amdgcn_mfma_f32_32x32x16_bf16(a[ks], b1, acc1, 0, 0, 0);
        }

        // write P: D col = ct*32 + (l&31), row = (reg&3)+8*(reg>>2)+4*hi
        const int prow0 = tsk + rbase + w * 32;
#pragma unroll
        for (int reg = 0; reg < 16; ++reg) {
            const int rowD = (reg & 3) + 8 * (reg >> 2) + 4 * hi;
            if (rbase + w * 32 + rowD < cntk) {
                ushort* pp = P + (size_t)(prow0 + rowD) * 64 + lrow;
                pp[0]  = f2bf(acc0[reg]);
                pp[32] = f2bf(acc1[reg]);
            }
        }
        __syncthreads();   // reads done before next tile's stage
    }
}

// ---------------------------------------------------------------------------
// pair-reduce: out[r] = act( sum_{k valid} P[pos[k][r]] + bias ).
// ---------------------------------------------------------------------------
template<int K, bool LEAKY, bool OUTF32>
__global__ __launch_bounds__(256) void pair_reduce(
    const int* __restrict__ pos, int nout,
    const ushort* __restrict__ P,
    const float* __restrict__ bias,
    void* __restrict__ fout)
{
    const int r = blockIdx.x * 256 + threadIdx.x;
    if (r >= nout) return;
    float acc[64];
#pragma unroll
    for (int c = 0; c < 64; ++c) acc[c] = 0.f;
#pragma unroll
    for (int k = 0; k < K; ++k) {
        const int p = pos[(size_t)k * nout + r];
        if (p >= 0) {
            const ushort* pr = P + (size_t)p * 64;
#pragma unroll
            for (int q = 0; q < 8; ++q) {
                const bf16x8 v = *reinterpret_cast<const bf16x8*>(pr + q * 8);
#pragma unroll
                for (int e = 0; e < 8; ++e)
                    acc[q * 8 + e] += bf2f((ushort)v[e]);
            }
        }
    }
    if (OUTF32) {
        float* o = reinterpret_cast<float*>(fout) + (size_t)r * 64;
#pragma unroll
        for (int c = 0; c < 64; ++c) {
            float v = acc[c] + bias[c];
            if (LEAKY) v = v >= 0.f ? v : LRELU_SLOPE * v;
            o[c] = v;
        }
    } else {
        ushort* o = reinterpret_cast<ushort*>(fout) + (size_t)r * 64;
#pragma unroll
        for (int c = 0; c < 64; ++c) {
            float v = acc[c] + bias[c];
            if (LEAKY) v = v >= 0.f ? v : LRELU_SLOPE * v;
            o[c] = f2bf(v);
        }
    }
}

// ---------------------------------------------------------------------------
// BatchNorm stage 1 (bf16 input): deterministic per-block partial sum/sumsq.
// ---------------------------------------------------------------------------
__global__ __launch_bounds__(256) void bn_partial(const ushort* __restrict__ f2v, int n2,
                                                  float* __restrict__ partials)
{
    const int c = threadIdx.x & 63;
    const int g = threadIdx.x >> 6;
    float s = 0.f, ss = 0.f;
    for (int r = blockIdx.x * 4 + g; r < n2; r += gridDim.x * 4) {
        const float v = bf2f(f2v[(size_t)r * 64 + c]);
        s += v;
        ss = fmaf(v, v, ss);
    }
    __shared__ float red[4][128];
    red[g][c] = s;
    red[g][64 + c] = ss;
    __syncthreads();
    if (g == 0) {
        partials[(size_t)blockIdx.x * 128 + c] =
            red[0][c] + red[1][c] + red[2][c] + red[3][c];
        partials[(size_t)blockIdx.x * 128 + 64 + c] =
            red[0][64 + c] + red[1][64 + c] + red[2][64 + c] + red[3][64 + c];
    }
}

// ---------------------------------------------------------------------------
// BatchNorm stage 2: PARALLEL final reduce -> per-channel affine (scale folded)
// ---------------------------------------------------------------------------
__global__ __launch_bounds__(1024) void bn_finalize(const float* __restrict__ partials, int n2,
                                                    const float* __restrict__ gamma,
                                                    const float* __restrict__ beta,
                                                    const float* __restrict__ scale,
                                                    float* __restrict__ affA, float* __restrict__ affB)
{
    const int t = threadIdx.x;
    const int col = t & 127;
    const int g = t >> 7;
    float s = 0.f;
#pragma unroll
    for (int b = g; b < BN_NB; b += 8)
        s += partials[(size_t)b * 128 + col];
    __shared__ float red[8][128];
    red[g][col] = s;
    __syncthreads();
    if (g == 0) {
        float S = red[0][col];
#pragma unroll
        for (int i = 1; i < 8; ++i) S += red[i][col];
        red[0][col] = S;
    }
    __syncthreads();
    if (t < 64) {
        const float S = red[0][t];
        const float SS = red[0][64 + t];
        const float inv_n = 1.f / (float)n2;
        const float mu = S * inv_n;
        const float var = fmaxf(SS * inv_n - mu * mu, 0.f);
        const float rs = rsqrtf(var + 1e-5f);
        const float sc = scale[0];
        const float ga = gamma[t];
        affA[t] = rs * ga * sc;
        affB[t] = (beta[t] - mu * rs * ga) * sc;
    }
}

// ---------------------------------------------------------------------------
// In-place BN affine on f2 (bf16): f2 = f2*a + b.
// ---------------------------------------------------------------------------
__global__ __launch_bounds__(256) void aff_apply(ushort* __restrict__ f2, int nchunk,
                                                 const float* __restrict__ affA,
                                                 const float* __restrict__ affB)
{
    for (int i = blockIdx.x * 256 + threadIdx.x; i < nchunk; i += gridDim.x * 256) {
        const int c = i & 7;
        bf16x8 v = *reinterpret_cast<const bf16x8*>(f2 + (size_t)i * 8);
#pragma unroll
        for (int j = 0; j < 8; ++j)
            v[j] = (short)f2bf(fmaf(bf2f((ushort)v[j]), affA[c * 8 + j], affB[c * 8 + j]));
        *reinterpret_cast<bf16x8*>(f2 + (size_t)i * 8) = v;
    }
}

extern "C" void kernel_launch(void* const* d_in, const int* in_sizes, int n_in,
                              void* d_out, int out_size, void* d_ws, size_t ws_size,
                              hipStream_t stream)
{
    const float* x     = (const float*)d_in[0];
    const float* W1    = (const float*)d_in[1];
    const float* b1    = (const float*)d_in[2];
    const float* W2    = (const float*)d_in[3];
    const float* b2    = (const float*)d_in[4];
    const float* W3    = (const float*)d_in[5];
    const float* b3    = (const float*)d_in[6];
    const float* gamma = (const float*)d_in[7];
    const float* beta  = (const float*)d_in[8];
    const float* scale = (const float*)d_in[9];
    const int* nmap1   = (const int*)d_in[10];
    const int* nmap2   = (const int*)d_in[11];
    const int* nmap3   = (const int*)d_in[12];

    const int N  = in_sizes[0] / 96;    // stride-1 points
    const int N2 = in_sizes[11] / 8;    // stride-2 points
    const int E1 = 27 * N;              // max pairs (sizes pos/IL/P)

    // ---- workspace layout (every region 16B-aligned) ----
    ushort* xb  = (ushort*)d_ws;                    // [N+1,96] bf16
    ushort* f1  = xb + (size_t)(N + 1) * 96;        // [N+1,64] bf16
    ushort* f2  = f1 + (size_t)(N + 1) * 64;        // [N2+1,64] bf16
    ushort* Bp1 = f2 + (size_t)(N2 + 1) * 64;       // 27*96*64
    ushort* Bp2 = Bp1 + 27 * 96 * 64;               // 8*64*64
    ushort* Bp3 = Bp2 + 8 * 64 * 64;                // 27*64*64
    float* partials = (float*)(Bp3 + 27 * 64 * 64); // [BN_NB,128] f32
    float* affA = partials + (size_t)BN_NB * 128;   // [64]
    float* affB = affA + 64;                        // [64]
    int* meta   = (int*)(affB + 64);                // 128 ints
    int* tmap   = meta + 128;                       // 16384 ints
    int* cnt2d  = tmap + 16384;                     // 8192 ints
    int* base2d = cnt2d + 8192;                     // 8192 ints
    int* pos    = base2d + 8192;                    // E1 ints
    int* IL     = pos + E1;                         // E1 ints
    ushort* P   = (ushort*)(IL + E1);               // [E1, 64] bf16
    float* out  = (float*)d_out;                    // [N2,64] fp32

    const int gN  = (N + 255) / 256;
    const int gN2 = (N2 + 255) / 256;

    // ---- prologue ----
    zero_rows<<<1, 128, 0, stream>>>(xb + (size_t)N * 96, f1 + (size_t)N * 64,
                                     f2 + (size_t)N2 * 64);
    cvt_bf16<<<2048, 256, 0, stream>>>(x, xb, N * 96 / 4);
    pack_W<27, 96><<<(27 * 12 * 64 + 255) / 256, 256, 0, stream>>>(W1, Bp1);
    pack_W<8, 64><<<(8 * 8 * 64 + 255) / 256, 256, 0, stream>>>(W2, Bp2);
    pack_W<27, 64><<<(27 * 8 * 64 + 255) / 256, 256, 0, stream>>>(W3, Bp3);

    // ---- conv1: k=27, 96->64, leaky ----
    pk1_count<27><<<gN, 256, 0, stream>>>(nmap1, N, N, gN, cnt2d);
    pk2_scan<27><<<1, 256, 0, stream>>>(cnt2d, gN, base2d, meta, tmap);
    pk3_fill<27><<<gN, 256, 0, stream>>>(nmap1, N, N, gN, base2d, pos, IL);
    pair_gemm<27, 96><<<2048, 256, 0, stream>>>(xb, N, IL, meta, tmap, Bp1, P);
    pair_reduce<27, true, false><<<gN, 256, 0, stream>>>(pos, N, P, b1, f1);

    // ---- conv2: k=8, 64->64, leaky (downsample) ----
    pk1_count<8><<<gN2, 256, 0, stream>>>(nmap2, N2, N, gN2, cnt2d);
    pk2_scan<8><<<1, 256, 0, stream>>>(cnt2d, gN2, base2d, meta, tmap);
    pk3_fill<8><<<gN2, 256, 0, stream>>>(nmap2, N2, N, gN2, base2d, pos, IL);
    pair_gemm<8, 64><<<2048, 256, 0, stream>>>(f1, N, IL, meta, tmap, Bp2, P);
    pair_reduce<8, true, false><<<gN2, 256, 0, stream>>>(pos, N2, P, b2, f2);

    // ---- batchnorm (deterministic two-stage) + in-place affine ----
    bn_partial<<<BN_NB, 256, 0, stream>>>(f2, N2, partials);
    bn_finalize<<<1, 1024, 0, stream>>>(partials, N2, gamma, beta, scale, affA, affB);
    aff_apply<<<2048, 256, 0, stream>>>(f2, N2 * 8, affA, affB);

    // ---- conv3: k=27, 64->64, fp32 out ----
    pk1_count<27><<<gN2, 256, 0, stream>>>(nmap3, N2, N2, gN2, cnt2d);
    pk2_scan<27><<<1, 256, 0, stream>>>(cnt2d, gN2, base2d, meta, tmap);
    pk3_fill<27><<<gN2, 256, 0, stream>>>(nmap3, N2, N2, gN2, base2d, pos, IL);
    pair_gemm<27, 64><<<2048, 256, 0, stream>>>(f2, N2, IL, meta, tmap, Bp3, P);
    pair_reduce<27, false, true><<<gN2, 256, 0, stream>>>(pos, N2, P, b3, out);
}